// Round 19
// baseline (79.928 us; speedup 1.0000x reference)
//
#include <hip/hip_runtime.h>

#define H        400
#define W_CROP   400
#define PSF_W    121
#define MARGIN   44
#define IM       488
#define NZ       64
#define N_EMIT   2048
#define PSF_AREA (PSF_W * PSF_W)     /* 14641 */
#define SIGMA2   100.0f              /* SIGMA_READ^2 */
#define TILE     16
#define TB       25                  /* tiles per side: 400/16 */
#define NTILES   (TB * TB)           /* 625 */
#define NPIX     (H * W_CROP)        /* 160000 */
#define PADW     152                 /* padded slice width (rows/cols -16..135) */
#define PADA     (PADW * PADW)       /* 23104 elems per padded slice */
#define CHUNKS   4                   /* z-chunks (zi>>4) */
#define CAPC     224                 /* max emitters per (tile, z-chunk) */
#define CAP_B    512                 /* max emitters per (tile-row, z-chunk) bucket */
#define NBUCK    (TB * CHUNKS)       /* 100 */
#define PADBLK   512                 /* pad/zsum blocks in prep kernel */
#define NMBLK    157                 /* noise/norm blocks = ceil(NPIX/4/256) */

typedef __fp16 h2 __attribute__((ext_vector_type(2)));

#if __has_builtin(__builtin_amdgcn_fdot2)
#define FDOT2(a, b, c) __builtin_amdgcn_fdot2((a), (b), (c), false)
#else
static __device__ __forceinline__ float FDOT2(h2 a, h2 b, float c) {
    return fmaf((float)a.x, (float)b.x, fmaf((float)a.y, (float)b.y, c));
}
#endif

static __device__ __forceinline__ unsigned pkh2(float lo, float hi) {
    const h2 v = __builtin_amdgcn_cvt_pkrtz(lo, hi);
    return __builtin_bit_cast(unsigned, v);
}

static __device__ __forceinline__ unsigned enc_ord(float f) {
    unsigned u = __float_as_uint(f);
    return (u & 0x80000000u) ? ~u : (u | 0x80000000u);
}
static __device__ __forceinline__ float dec_ord(unsigned u) {
    return __uint_as_float((u & 0x80000000u) ? (u & 0x7fffffffu) : ~u);
}

static __device__ __forceinline__ void geom_of(const float* __restrict__ xyz, int e,
                                               int& r0, int& c0, int& zi,
                                               float& r0f, float& c0f) {
    const float x = xyz[3 * e + 0];
    const float y = xyz[3 * e + 1];
    const float z = xyz[3 * e + 2];
    const float lx = (x * 100.0f) / 11.0f;
    const float ly = (y * 100.0f) / 11.0f;
    r0f = (ly + 244.0f) - 60.5f;
    c0f = (lx + 244.0f) - 60.5f;
    r0 = (int)floorf(r0f);
    c0 = (int)floorf(c0f);
    zi = (int)rintf((z + 2.0f) / 4.0f * 63.0f);
    zi = min(max(zi, 0), NZ - 1);
}

/* 612 blocks, two overlapped roles (proven r13/r15 structure).
   bid < 512: (zi = bid>>3, part = bid&7) build PACKED-f16x2 padded slice
              part (u32 elem i = {f16 psf[r][c-1] | f16 psf[r][c] << 16})
              + per-part f32 sums -> zpart. Block 0 inits minmax + done. No atomics.
   bid >= 512: bucket build. b = bid-512 = (tr, zc); scan all emitters,
              prefix-scan compact (e-ordered, deterministic) into bucket[b]. */
__global__ __launch_bounds__(256) void prep_kernel(
        const float* __restrict__ psf_bank, float* __restrict__ zpart,
        unsigned* __restrict__ pad, unsigned* __restrict__ minmax,
        const float* __restrict__ xyz, const float* __restrict__ nph_arr,
        float4* __restrict__ bucket, int* __restrict__ bcnt)
{
    __shared__ float red[4][4];
    __shared__ int   wtot[4];

    if (blockIdx.x < PADBLK) {
        const int zi   = blockIdx.x >> 3;
        const int part = blockIdx.x & 7;

        if (blockIdx.x == 0 && threadIdx.x == 0) {
            minmax[0] = 0xFFFFFFFFu; minmax[1] = 0u; minmax[2] = 0u; /* done */
        }

        const float* __restrict__ src = psf_bank + (size_t)zi * PSF_AREA;
        unsigned* __restrict__ dst = pad + (size_t)zi * PADA;

        const int plo = part * 2888;                 /* 2888 = 19*152 */
        const int phi = min(plo + 2888, PADA);
        for (int i = plo + (int)threadIdx.x; i < phi; i += 256) {
            const int rp = i / PADW;
            const int r = rp - 16;
            const int c = i - rp * PADW - 16;
            const bool rin = (unsigned)r < (unsigned)PSF_W;
            const float vm = (rin && (unsigned)(c - 1) < (unsigned)PSF_W) ? src[r * PSF_W + c - 1] : 0.0f;
            const float vc = (rin && (unsigned)c < (unsigned)PSF_W)       ? src[r * PSF_W + c]     : 0.0f;
            dst[i] = pkh2(vm, vc);
        }

        const int slo = part * 1831;
        const int shi = min(slo + 1831, PSF_AREA);
        float S = 0.f, R = 0.f, C = 0.f, K = 0.f;
        for (int i = slo + (int)threadIdx.x; i < shi; i += 256) {
            const float v = src[i];
            const int r = i / PSF_W;
            const int c = i - r * PSF_W;
            S += v;
            if (r == PSF_W - 1) R += v;
            if (c == PSF_W - 1) C += v;
            if (r == PSF_W - 1 && c == PSF_W - 1) K += v;
        }
        #pragma unroll
        for (int off = 32; off > 0; off >>= 1) {
            S += __shfl_down(S, off, 64);
            R += __shfl_down(R, off, 64);
            C += __shfl_down(C, off, 64);
            K += __shfl_down(K, off, 64);
        }
        const int wave = threadIdx.x >> 6, lane = threadIdx.x & 63;
        if (lane == 0) { red[wave][0] = S; red[wave][1] = R; red[wave][2] = C; red[wave][3] = K; }
        __syncthreads();
        if (threadIdx.x == 0) {
            float4 o;
            o.x = (red[0][0] + red[1][0]) + (red[2][0] + red[3][0]);
            o.y = (red[0][1] + red[1][1]) + (red[2][1] + red[3][1]);
            o.z = (red[0][2] + red[1][2]) + (red[2][2] + red[3][2]);
            o.w = (red[0][3] + red[1][3]) + (red[2][3] + red[3][3]);
            *(float4*)(zpart + (size_t)(zi * 8 + part) * 4) = o;
        }
        return;
    }

    /* ---- bucket role ---- */
    const int b   = blockIdx.x - PADBLK;         /* 0..99 */
    const int btr = b >> 2, bzc = b & 3;
    const int w    = threadIdx.x >> 6;
    const int lane = threadIdx.x & 63;

    int mycnt = 0;
    unsigned mymask = 0u;
    #pragma unroll
    for (int q = 0; q < 8; ++q) {
        const int e = (int)threadIdx.x * 8 + q;
        int r0, c0, zi; float r0f, c0f;
        geom_of(xyz, e, r0, c0, zi, r0f, c0f);
        const bool p = ((zi >> 4) == bzc)
                     && (btr >= ((r0 - MARGIN) >> 4)) && (btr <= ((r0 + 76) >> 4));
        mymask |= (unsigned)p << q;
        mycnt += (int)p;
    }

    int incl = mycnt;
    #pragma unroll
    for (int off = 1; off < 64; off <<= 1) {
        const int v = __shfl_up(incl, off, 64);
        if (lane >= off) incl += v;
    }
    if (lane == 63) wtot[w] = incl;
    __syncthreads();
    int base = incl - mycnt;
    #pragma unroll
    for (int ww = 0; ww < 4; ++ww) base += (ww < w) ? wtot[ww] : 0;
    const int ntot = wtot[0] + wtot[1] + wtot[2] + wtot[3];

    if (mymask) {
        int slot = base;
        #pragma unroll
        for (int q = 0; q < 8; ++q) {
            if (mymask & (1u << q)) {
                const int e = (int)threadIdx.x * 8 + q;
                int r0, c0, zi; float r0f, c0f;
                geom_of(xyz, e, r0, c0, zi, r0f, c0f);
                if (slot < CAP_B) {
                    const float rs = r0f - floorf(r0f);
                    const float cs = c0f - floorf(c0f);
                    const float nph = nph_arr[e];
                    float4 s0, s1;
                    s0.x = nph * (1.0f - rs) * (1.0f - cs);
                    s0.y = nph * (1.0f - rs) * cs;
                    s0.z = nph * rs * (1.0f - cs);
                    s0.w = nph * rs * cs;
                    const int packed = ((r0 + 16) << 15) | ((c0 + 16) << 6) | zi;
                    s1.x = rs; s1.y = cs; s1.z = __int_as_float(packed); s1.w = 0.f;
                    bucket[(size_t)(b * CAP_B + slot) * 2]     = s0;
                    bucket[(size_t)(b * CAP_B + slot) * 2 + 1] = s1;
                }
                ++slot;
            }
        }
    }
    if (threadIdx.x == 0) bcnt[b] = min(ntot, CAP_B);
}

/* grid = 2504 blocks x 256 thr. XCD affinity: zc = (bid&7)>>1 pins each XCD
   pair to ONE z-chunk -> per-XCD pad working set = 1.48 MB (L2-resident).
   Staging: scan bucket (tr, zc), column test, wave-scan compaction, 1/ssum
   applied, weights packed to half2 -> ONE float4 per entry.
   Body: 1 LDS float4 + 5 dword loads + 8 v_dot2_f32_f16 + footprint mask.
   4-deep ILP unroll. Block partial -> LDS reduce -> partial image zc. */
__global__ __launch_bounds__(256) void gather_kernel(
        const unsigned* __restrict__ pad, const float4* __restrict__ bucket,
        const int* __restrict__ bcnt, const float* __restrict__ zpart,
        float* __restrict__ parts)
{
    const int zc   = (blockIdx.x & 7) >> 1;
    const int tile = 2 * (blockIdx.x >> 3) + (blockIdx.x & 1);
    if (tile >= NTILES) return;

    __shared__ float4 smeta[CAPC];               /* 3.6 KB */
    __shared__ float  tilepart[4][256];          /* 4 KB */
    __shared__ int    wtot[4];

    const int tr = tile / TB, tc = tile - tr * TB;
    const int w    = threadIdx.x >> 6;
    const int lane = threadIdx.x & 63;
    const int px = lane & 15;                    /* col within tile */
    const int wy = lane >> 4;                    /* 0..3: 4-row strip */
    const int orow0 = tr * TILE + wy * 4;
    const int ocol  = tc * TILE + px;
    const int crow0 = orow0 + MARGIN;            /* canvas coords */
    const int ccol  = ocol + MARGIN;
    const int tcb   = (crow0 * PADW + ccol) * 4; /* thread-const byte offset */
    const char* __restrict__ pbase = (const char*)pad;

    const int b   = tr * CHUNKS + zc;            /* bucket id */
    const int n_b = bcnt[b];
    const float4* __restrict__ bk = bucket + (size_t)b * CAP_B * 2;

    /* ---- staging: filter bucket entries by column range, compact e-ordered ---- */
    int nstaged = 0;
    for (int base_i = 0; base_i < n_b; base_i += 256) {
        const int i = base_i + (int)threadIdx.x;
        float4 m0, m1;
        int r0 = 0, c0 = 0, zi = 0;
        bool p = false;
        if (i < n_b) {
            m0 = bk[2 * i];
            m1 = bk[2 * i + 1];
            const int packed = __float_as_int(m1.z);
            zi = packed & 63;
            c0 = ((packed >> 6) & 511) - 16;
            r0 = ((packed >> 15) & 511) - 16;
            p = (tc >= ((c0 - MARGIN) >> 4)) && (tc <= ((c0 + 76) >> 4));
        }
        int incl = (int)p;
        #pragma unroll
        for (int off = 1; off < 64; off <<= 1) {
            const int v = __shfl_up(incl, off, 64);
            if (lane >= off) incl += v;
        }
        if (lane == 63) wtot[w] = incl;
        __syncthreads();
        int slot = nstaged + incl - (int)p;
        #pragma unroll
        for (int ww = 0; ww < 4; ++ww) slot += (ww < w) ? wtot[ww] : 0;
        const int round_tot = wtot[0] + wtot[1] + wtot[2] + wtot[3];
        if (p && slot < CAPC) {
            const float rs = m1.x, cs = m1.y;
            const float4* __restrict__ zp = (const float4*)zpart + zi * 8;
            float4 zm = zp[0];
            #pragma unroll
            for (int u = 1; u < 8; ++u) {
                const float4 t = zp[u];
                zm.x += t.x; zm.y += t.y; zm.z += t.z; zm.w += t.w;
            }
            const float ssum = zm.x - rs * zm.y - cs * zm.z + rs * cs * zm.w;
            const float inv = 1.0f / ssum;
            float4 s;
            s.x = __uint_as_float(pkh2(m0.y * inv, m0.x * inv));   /* {w01, w00} */
            s.y = __uint_as_float(pkh2(m0.w * inv, m0.z * inv));   /* {w11, w10} */
            s.z = __int_as_float((zi * PADA + (15 - r0) * PADW + (16 - c0)) * 4);
            s.w = __int_as_float(((r0 + 16) << 16) | (c0 + 16));
            smeta[slot] = s;
        }
        nstaged += round_tot;
        __syncthreads();
    }
    const int n = min(nstaged, CAPC);

    float acc0[4] = {0.f, 0.f, 0.f, 0.f};
    float acc1[4] = {0.f, 0.f, 0.f, 0.f};
    float acc2[4] = {0.f, 0.f, 0.f, 0.f};
    float acc3[4] = {0.f, 0.f, 0.f, 0.f};

    auto body = [&](int j, float* acc) {
        const float4 s = smeta[j];
        const h2 wA = __builtin_bit_cast(h2, s.x);      /* {w01, w00} */
        const h2 wB = __builtin_bit_cast(h2, s.y);      /* {w11, w10} */
        const int off = __float_as_int(s.z);
        const int rc  = __float_as_int(s.w);
        const int pr0 = crow0 - ((rc >> 16) - 16);      /* row of strip pixel 0 */
        const int pc  = ccol  - ((rc & 0xFFFF) - 16);
        const char* __restrict__ p = pbase + (tcb + off);
        h2 f[5];
        #pragma unroll
        for (int i = 0; i < 5; ++i)
            f[i] = __builtin_bit_cast(h2, *(const unsigned*)(p + i * (PADW * 4)));
        const bool pcok = (unsigned)pc <= 120u;
        #pragma unroll
        for (int k = 0; k < 4; ++k) {
            float v = FDOT2(wA, f[k + 1], 0.0f);  /* w01*psf[pr][pc-1] + w00*psf[pr][pc] */
            v = FDOT2(wB, f[k], v);               /* w11*psf[pr-1][pc-1] + w10*psf[pr-1][pc] */
            /* crop to 121x121 footprint (reference crops the shifted PSF) */
            const bool ok = pcok & ((unsigned)(pr0 + k) <= 120u);
            acc[k] += ok ? v : 0.f;
        }
    };

    int j = w;
    for (; j + 12 < n; j += 16) {
        body(j, acc0); body(j + 4, acc1); body(j + 8, acc2); body(j + 12, acc3);
    }
    for (; j < n; j += 4) body(j, acc0);

    #pragma unroll
    for (int k = 0; k < 4; ++k)
        tilepart[w][(wy * 4 + k) * 16 + px] = (acc0[k] + acc1[k]) + (acc2[k] + acc3[k]);
    __syncthreads();

    /* fixed-order reduce of the 4 waves, write partial image zc */
    const int row = threadIdx.x >> 4, col = threadIdx.x & 15;
    const float s = ((tilepart[0][threadIdx.x] + tilepart[1][threadIdx.x]) +
                     (tilepart[2][threadIdx.x] + tilepart[3][threadIdx.x]));
    parts[(size_t)zc * NPIX + (tr * TILE + row) * W_CROP + (tc * TILE + col)] = s;
}

/* FUSED noise + minmax + normalize: 157 blocks (trivially co-resident).
   Each block: sum 4 partials (fixed order), add noise (im kept in registers),
   block min/max -> device atomicMin/Max (order-independent => deterministic),
   threadfence + arrive, spin until all 157 blocks arrived, then normalize
   from registers and write out ONCE. done counter = minmax[2], reset by prep. */
__global__ __launch_bounds__(256) void noise_norm_kernel(
        const float* __restrict__ parts, const float* __restrict__ noise,
        float* __restrict__ out, unsigned* __restrict__ minmax)
{
    const int i = blockIdx.x * 256 + threadIdx.x;
    const bool act = i < NPIX / 4;
    float4 im = make_float4(0.f, 0.f, 0.f, 0.f);
    float vmin = 1e30f, vmax = -1e30f;
    if (act) {
        const float4 p0 = ((const float4*)parts)[i];
        const float4 p1 = ((const float4*)(parts + NPIX))[i];
        const float4 p2 = ((const float4*)(parts + 2 * NPIX))[i];
        const float4 p3 = ((const float4*)(parts + 3 * NPIX))[i];
        im.x = (p0.x + p1.x) + (p2.x + p3.x);
        im.y = (p0.y + p1.y) + (p2.y + p3.y);
        im.z = (p0.z + p1.z) + (p2.z + p3.z);
        im.w = (p0.w + p1.w) + (p2.w + p3.w);
        const float4 nz = ((const float4*)noise)[i];
        im.x += sqrtf(fmaxf(im.x, 0.f) + SIGMA2) * nz.x;
        im.y += sqrtf(fmaxf(im.y, 0.f) + SIGMA2) * nz.y;
        im.z += sqrtf(fmaxf(im.z, 0.f) + SIGMA2) * nz.z;
        im.w += sqrtf(fmaxf(im.w, 0.f) + SIGMA2) * nz.w;
        vmin = fminf(fminf(im.x, im.y), fminf(im.z, im.w));
        vmax = fmaxf(fmaxf(im.x, im.y), fmaxf(im.z, im.w));
    }
    #pragma unroll
    for (int off = 32; off > 0; off >>= 1) {
        vmin = fminf(vmin, __shfl_down(vmin, off, 64));
        vmax = fmaxf(vmax, __shfl_down(vmax, off, 64));
    }
    if ((threadIdx.x & 63) == 0) {
        atomicMin(&minmax[0], enc_ord(vmin));
        atomicMax(&minmax[1], enc_ord(vmax));
    }
    __syncthreads();
    if (threadIdx.x == 0) {
        __threadfence();
        atomicAdd(&minmax[2], 1u);
    }
    /* spin until all blocks have published their min/max */
    while (__hip_atomic_load(&minmax[2], __ATOMIC_ACQUIRE, __HIP_MEMORY_SCOPE_AGENT) < (unsigned)NMBLK)
        __builtin_amdgcn_s_sleep(1);

    const float mn  = dec_ord(__hip_atomic_load(&minmax[0], __ATOMIC_RELAXED, __HIP_MEMORY_SCOPE_AGENT));
    const float mx  = dec_ord(__hip_atomic_load(&minmax[1], __ATOMIC_RELAXED, __HIP_MEMORY_SCOPE_AGENT));
    const float inv = 1.0f / (mx - mn);
    if (act) {
        float4 v;
        v.x = (im.x - mn) * inv;
        v.y = (im.y - mn) * inv;
        v.z = (im.z - mn) * inv;
        v.w = (im.w - mn) * inv;
        ((float4*)out)[i] = v;
    }
}

extern "C" void kernel_launch(void* const* d_in, const int* in_sizes, int n_in,
                              void* d_out, int out_size, void* d_ws, size_t ws_size,
                              hipStream_t stream) {
    const float* xyz      = (const float*)d_in[0];  /* (1,2048,3) */
    const float* nph      = (const float*)d_in[1];  /* (1,2048)   */
    /* d_in[2] = xy_center, unused by reference */
    const float* psf_bank = (const float*)d_in[3];  /* (64,121,121) */
    const float* noise    = (const float*)d_in[4];  /* (400,400) */
    float* out = (float*)d_out;

    /* ws layout (bytes):
       minmax: 0        .. 12         ([0]=min, [1]=max, [2]=done counter)
       zpart : 1024     .. 9216       (64 * 8 * float4)
       pad   : 9216     .. 5923840    (64 * 152 * 152 u32 f16x2)
       bucket: 5923840  .. 7562240    (100 * 512 * 2 float4)
       bcnt  : 7562240  .. 7562640    (100 ints)
       parts : 7563264  .. 10123264   (4 * 400*400 f32)            */
    char* ws = (char*)d_ws;
    unsigned* minmax = (unsigned*)(ws + 0);
    float*    zpart  = (float*)(ws + 1024);
    unsigned* pad    = (unsigned*)(ws + 9216);
    float4*   bucket = (float4*)(ws + 5923840);
    int*      bcnt   = (int*)(ws + 7562240);
    float*    parts  = (float*)(ws + 7563264);

    prep_kernel<<<PADBLK + NBUCK, 256, 0, stream>>>(psf_bank, zpart, pad, minmax,
                                                    xyz, nph, bucket, bcnt);
    gather_kernel<<<2504, 256, 0, stream>>>(pad, bucket, bcnt, zpart, parts);
    noise_norm_kernel<<<NMBLK, 256, 0, stream>>>(parts, noise, out, minmax);
}

// Round 20
// 61.255 us; speedup vs baseline: 1.3048x; 1.3048x over previous
//
#include <hip/hip_runtime.h>

#define H        400
#define W_CROP   400
#define PSF_W    121
#define MARGIN   44
#define IM       488
#define NZ       64
#define N_EMIT   2048
#define PSF_AREA (PSF_W * PSF_W)     /* 14641 */
#define SIGMA2   100.0f              /* SIGMA_READ^2 */
#define TILE     16
#define TB       25                  /* tiles per side: 400/16 */
#define NTILES   (TB * TB)           /* 625 */
#define NPIX     (H * W_CROP)        /* 160000 */
#define PADW     152                 /* padded slice width (rows/cols -16..135) */
#define PADA     (PADW * PADW)       /* 23104 elems per padded slice */
#define CHUNKS   4                   /* z-chunks (zi>>4) */
#define CAPC     224                 /* max emitters per (tile, z-chunk) */
#define CAP_B    512                 /* max emitters per (tile-row, z-chunk) bucket */
#define NBUCK    (TB * CHUNKS)       /* 100 */
#define PADBLK   512                 /* pad/zsum blocks in prep kernel */
#define NMBLK    157                 /* noise/norm blocks = ceil(NPIX/4/256), < 256 CUs -> co-resident */

typedef __fp16 h2 __attribute__((ext_vector_type(2)));

#if __has_builtin(__builtin_amdgcn_fdot2)
#define FDOT2(a, b, c) __builtin_amdgcn_fdot2((a), (b), (c), false)
#else
static __device__ __forceinline__ float FDOT2(h2 a, h2 b, float c) {
    return fmaf((float)a.x, (float)b.x, fmaf((float)a.y, (float)b.y, c));
}
#endif

static __device__ __forceinline__ unsigned pkh2(float lo, float hi) {
    const h2 v = __builtin_amdgcn_cvt_pkrtz(lo, hi);
    return __builtin_bit_cast(unsigned, v);
}

static __device__ __forceinline__ unsigned enc_ord(float f) {
    unsigned u = __float_as_uint(f);
    return (u & 0x80000000u) ? ~u : (u | 0x80000000u);
}
static __device__ __forceinline__ float dec_ord(unsigned u) {
    return __uint_as_float((u & 0x80000000u) ? (u & 0x7fffffffu) : ~u);
}

static __device__ __forceinline__ void geom_of(const float* __restrict__ xyz, int e,
                                               int& r0, int& c0, int& zi,
                                               float& r0f, float& c0f) {
    const float x = xyz[3 * e + 0];
    const float y = xyz[3 * e + 1];
    const float z = xyz[3 * e + 2];
    const float lx = (x * 100.0f) / 11.0f;
    const float ly = (y * 100.0f) / 11.0f;
    r0f = (ly + 244.0f) - 60.5f;
    c0f = (lx + 244.0f) - 60.5f;
    r0 = (int)floorf(r0f);
    c0 = (int)floorf(c0f);
    zi = (int)rintf((z + 2.0f) / 4.0f * 63.0f);
    zi = min(max(zi, 0), NZ - 1);
}

/* 612 blocks, two overlapped roles (proven r13/r15 structure).
   bid < 512: (zi = bid>>3, part = bid&7) build PACKED-f16x2 padded slice
              part (u32 elem i = {f16 psf[r][c-1] | f16 psf[r][c] << 16})
              + per-part f32 sums -> zpart. Block 0 inits minmax + done. No atomics.
   bid >= 512: bucket build. b = bid-512 = (tr, zc); scan all emitters,
              prefix-scan compact (e-ordered, deterministic) into bucket[b]. */
__global__ __launch_bounds__(256) void prep_kernel(
        const float* __restrict__ psf_bank, float* __restrict__ zpart,
        unsigned* __restrict__ pad, unsigned* __restrict__ minmax,
        const float* __restrict__ xyz, const float* __restrict__ nph_arr,
        float4* __restrict__ bucket, int* __restrict__ bcnt)
{
    __shared__ float red[4][4];
    __shared__ int   wtot[4];

    if (blockIdx.x < PADBLK) {
        const int zi   = blockIdx.x >> 3;
        const int part = blockIdx.x & 7;

        if (blockIdx.x == 0 && threadIdx.x == 0) {
            minmax[0] = 0xFFFFFFFFu; minmax[1] = 0u; minmax[2] = 0u; /* done */
        }

        const float* __restrict__ src = psf_bank + (size_t)zi * PSF_AREA;
        unsigned* __restrict__ dst = pad + (size_t)zi * PADA;

        const int plo = part * 2888;                 /* 2888 = 19*152 */
        const int phi = min(plo + 2888, PADA);
        for (int i = plo + (int)threadIdx.x; i < phi; i += 256) {
            const int rp = i / PADW;
            const int r = rp - 16;
            const int c = i - rp * PADW - 16;
            const bool rin = (unsigned)r < (unsigned)PSF_W;
            const float vm = (rin && (unsigned)(c - 1) < (unsigned)PSF_W) ? src[r * PSF_W + c - 1] : 0.0f;
            const float vc = (rin && (unsigned)c < (unsigned)PSF_W)       ? src[r * PSF_W + c]     : 0.0f;
            dst[i] = pkh2(vm, vc);
        }

        const int slo = part * 1831;
        const int shi = min(slo + 1831, PSF_AREA);
        float S = 0.f, R = 0.f, C = 0.f, K = 0.f;
        for (int i = slo + (int)threadIdx.x; i < shi; i += 256) {
            const float v = src[i];
            const int r = i / PSF_W;
            const int c = i - r * PSF_W;
            S += v;
            if (r == PSF_W - 1) R += v;
            if (c == PSF_W - 1) C += v;
            if (r == PSF_W - 1 && c == PSF_W - 1) K += v;
        }
        #pragma unroll
        for (int off = 32; off > 0; off >>= 1) {
            S += __shfl_down(S, off, 64);
            R += __shfl_down(R, off, 64);
            C += __shfl_down(C, off, 64);
            K += __shfl_down(K, off, 64);
        }
        const int wave = threadIdx.x >> 6, lane = threadIdx.x & 63;
        if (lane == 0) { red[wave][0] = S; red[wave][1] = R; red[wave][2] = C; red[wave][3] = K; }
        __syncthreads();
        if (threadIdx.x == 0) {
            float4 o;
            o.x = (red[0][0] + red[1][0]) + (red[2][0] + red[3][0]);
            o.y = (red[0][1] + red[1][1]) + (red[2][1] + red[3][1]);
            o.z = (red[0][2] + red[1][2]) + (red[2][2] + red[3][2]);
            o.w = (red[0][3] + red[1][3]) + (red[2][3] + red[3][3]);
            *(float4*)(zpart + (size_t)(zi * 8 + part) * 4) = o;
        }
        return;
    }

    /* ---- bucket role ---- */
    const int b   = blockIdx.x - PADBLK;         /* 0..99 */
    const int btr = b >> 2, bzc = b & 3;
    const int w    = threadIdx.x >> 6;
    const int lane = threadIdx.x & 63;

    int mycnt = 0;
    unsigned mymask = 0u;
    #pragma unroll
    for (int q = 0; q < 8; ++q) {
        const int e = (int)threadIdx.x * 8 + q;
        int r0, c0, zi; float r0f, c0f;
        geom_of(xyz, e, r0, c0, zi, r0f, c0f);
        const bool p = ((zi >> 4) == bzc)
                     && (btr >= ((r0 - MARGIN) >> 4)) && (btr <= ((r0 + 76) >> 4));
        mymask |= (unsigned)p << q;
        mycnt += (int)p;
    }

    int incl = mycnt;
    #pragma unroll
    for (int off = 1; off < 64; off <<= 1) {
        const int v = __shfl_up(incl, off, 64);
        if (lane >= off) incl += v;
    }
    if (lane == 63) wtot[w] = incl;
    __syncthreads();
    int base = incl - mycnt;
    #pragma unroll
    for (int ww = 0; ww < 4; ++ww) base += (ww < w) ? wtot[ww] : 0;
    const int ntot = wtot[0] + wtot[1] + wtot[2] + wtot[3];

    if (mymask) {
        int slot = base;
        #pragma unroll
        for (int q = 0; q < 8; ++q) {
            if (mymask & (1u << q)) {
                const int e = (int)threadIdx.x * 8 + q;
                int r0, c0, zi; float r0f, c0f;
                geom_of(xyz, e, r0, c0, zi, r0f, c0f);
                if (slot < CAP_B) {
                    const float rs = r0f - floorf(r0f);
                    const float cs = c0f - floorf(c0f);
                    const float nph = nph_arr[e];
                    float4 s0, s1;
                    s0.x = nph * (1.0f - rs) * (1.0f - cs);
                    s0.y = nph * (1.0f - rs) * cs;
                    s0.z = nph * rs * (1.0f - cs);
                    s0.w = nph * rs * cs;
                    const int packed = ((r0 + 16) << 15) | ((c0 + 16) << 6) | zi;
                    s1.x = rs; s1.y = cs; s1.z = __int_as_float(packed); s1.w = 0.f;
                    bucket[(size_t)(b * CAP_B + slot) * 2]     = s0;
                    bucket[(size_t)(b * CAP_B + slot) * 2 + 1] = s1;
                }
                ++slot;
            }
        }
    }
    if (threadIdx.x == 0) bcnt[b] = min(ntot, CAP_B);
}

/* grid = 2504 blocks x 256 thr. XCD affinity: zc = (bid&7)>>1 pins each XCD
   pair to ONE z-chunk -> per-XCD pad working set = 1.48 MB (L2-resident).
   Staging: scan bucket (tr, zc), column test, wave-scan compaction, 1/ssum
   applied, weights packed to half2 -> ONE float4 per entry.
   Body: 1 LDS float4 + 5 dword loads + 8 v_dot2_f32_f16 + footprint mask.
   4-deep ILP unroll. Block partial -> LDS reduce -> partial image zc. */
__global__ __launch_bounds__(256) void gather_kernel(
        const unsigned* __restrict__ pad, const float4* __restrict__ bucket,
        const int* __restrict__ bcnt, const float* __restrict__ zpart,
        float* __restrict__ parts)
{
    const int zc   = (blockIdx.x & 7) >> 1;
    const int tile = 2 * (blockIdx.x >> 3) + (blockIdx.x & 1);
    if (tile >= NTILES) return;

    __shared__ float4 smeta[CAPC];               /* 3.6 KB */
    __shared__ float  tilepart[4][256];          /* 4 KB */
    __shared__ int    wtot[4];

    const int tr = tile / TB, tc = tile - tr * TB;
    const int w    = threadIdx.x >> 6;
    const int lane = threadIdx.x & 63;
    const int px = lane & 15;                    /* col within tile */
    const int wy = lane >> 4;                    /* 0..3: 4-row strip */
    const int orow0 = tr * TILE + wy * 4;
    const int ocol  = tc * TILE + px;
    const int crow0 = orow0 + MARGIN;            /* canvas coords */
    const int ccol  = ocol + MARGIN;
    const int tcb   = (crow0 * PADW + ccol) * 4; /* thread-const byte offset */
    const char* __restrict__ pbase = (const char*)pad;

    const int b   = tr * CHUNKS + zc;            /* bucket id */
    const int n_b = bcnt[b];
    const float4* __restrict__ bk = bucket + (size_t)b * CAP_B * 2;

    /* ---- staging: filter bucket entries by column range, compact e-ordered ---- */
    int nstaged = 0;
    for (int base_i = 0; base_i < n_b; base_i += 256) {
        const int i = base_i + (int)threadIdx.x;
        float4 m0, m1;
        int r0 = 0, c0 = 0, zi = 0;
        bool p = false;
        if (i < n_b) {
            m0 = bk[2 * i];
            m1 = bk[2 * i + 1];
            const int packed = __float_as_int(m1.z);
            zi = packed & 63;
            c0 = ((packed >> 6) & 511) - 16;
            r0 = ((packed >> 15) & 511) - 16;
            p = (tc >= ((c0 - MARGIN) >> 4)) && (tc <= ((c0 + 76) >> 4));
        }
        int incl = (int)p;
        #pragma unroll
        for (int off = 1; off < 64; off <<= 1) {
            const int v = __shfl_up(incl, off, 64);
            if (lane >= off) incl += v;
        }
        if (lane == 63) wtot[w] = incl;
        __syncthreads();
        int slot = nstaged + incl - (int)p;
        #pragma unroll
        for (int ww = 0; ww < 4; ++ww) slot += (ww < w) ? wtot[ww] : 0;
        const int round_tot = wtot[0] + wtot[1] + wtot[2] + wtot[3];
        if (p && slot < CAPC) {
            const float rs = m1.x, cs = m1.y;
            const float4* __restrict__ zp = (const float4*)zpart + zi * 8;
            float4 zm = zp[0];
            #pragma unroll
            for (int u = 1; u < 8; ++u) {
                const float4 t = zp[u];
                zm.x += t.x; zm.y += t.y; zm.z += t.z; zm.w += t.w;
            }
            const float ssum = zm.x - rs * zm.y - cs * zm.z + rs * cs * zm.w;
            const float inv = 1.0f / ssum;
            float4 s;
            s.x = __uint_as_float(pkh2(m0.y * inv, m0.x * inv));   /* {w01, w00} */
            s.y = __uint_as_float(pkh2(m0.w * inv, m0.z * inv));   /* {w11, w10} */
            s.z = __int_as_float((zi * PADA + (15 - r0) * PADW + (16 - c0)) * 4);
            s.w = __int_as_float(((r0 + 16) << 16) | (c0 + 16));
            smeta[slot] = s;
        }
        nstaged += round_tot;
        __syncthreads();
    }
    const int n = min(nstaged, CAPC);

    float acc0[4] = {0.f, 0.f, 0.f, 0.f};
    float acc1[4] = {0.f, 0.f, 0.f, 0.f};
    float acc2[4] = {0.f, 0.f, 0.f, 0.f};
    float acc3[4] = {0.f, 0.f, 0.f, 0.f};

    auto body = [&](int j, float* acc) {
        const float4 s = smeta[j];
        const h2 wA = __builtin_bit_cast(h2, s.x);      /* {w01, w00} */
        const h2 wB = __builtin_bit_cast(h2, s.y);      /* {w11, w10} */
        const int off = __float_as_int(s.z);
        const int rc  = __float_as_int(s.w);
        const int pr0 = crow0 - ((rc >> 16) - 16);      /* row of strip pixel 0 */
        const int pc  = ccol  - ((rc & 0xFFFF) - 16);
        const char* __restrict__ p = pbase + (tcb + off);
        h2 f[5];
        #pragma unroll
        for (int i = 0; i < 5; ++i)
            f[i] = __builtin_bit_cast(h2, *(const unsigned*)(p + i * (PADW * 4)));
        const bool pcok = (unsigned)pc <= 120u;
        #pragma unroll
        for (int k = 0; k < 4; ++k) {
            float v = FDOT2(wA, f[k + 1], 0.0f);  /* w01*psf[pr][pc-1] + w00*psf[pr][pc] */
            v = FDOT2(wB, f[k], v);               /* w11*psf[pr-1][pc-1] + w10*psf[pr-1][pc] */
            /* crop to 121x121 footprint (reference crops the shifted PSF) */
            const bool ok = pcok & ((unsigned)(pr0 + k) <= 120u);
            acc[k] += ok ? v : 0.f;
        }
    };

    int j = w;
    for (; j + 12 < n; j += 16) {
        body(j, acc0); body(j + 4, acc1); body(j + 8, acc2); body(j + 12, acc3);
    }
    for (; j < n; j += 4) body(j, acc0);

    #pragma unroll
    for (int k = 0; k < 4; ++k)
        tilepart[w][(wy * 4 + k) * 16 + px] = (acc0[k] + acc1[k]) + (acc2[k] + acc3[k]);
    __syncthreads();

    /* fixed-order reduce of the 4 waves, write partial image zc */
    const int row = threadIdx.x >> 4, col = threadIdx.x & 15;
    const float s = ((tilepart[0][threadIdx.x] + tilepart[1][threadIdx.x]) +
                     (tilepart[2][threadIdx.x] + tilepart[3][threadIdx.x]));
    parts[(size_t)zc * NPIX + (tr * TILE + row) * W_CROP + (tc * TILE + col)] = s;
}

/* FUSED noise + minmax + normalize: 157 blocks (co-resident by construction).
   Each block: sum 4 partials (fixed order), add noise (im kept in registers),
   block min/max -> device atomicMin/Max (order-independent => deterministic),
   arrive, then ONE thread per block spin-polls (relaxed traffic: s_sleep
   between acquire loads) -- fixes r19's 40K-thread hot-line spin -- then LDS
   broadcast, normalize from registers, single write of out. */
__global__ __launch_bounds__(256) void noise_norm_kernel(
        const float* __restrict__ parts, const float* __restrict__ noise,
        float* __restrict__ out, unsigned* __restrict__ minmax)
{
    __shared__ float smm[2];
    const int i = blockIdx.x * 256 + threadIdx.x;
    const bool act = i < NPIX / 4;
    float4 im = make_float4(0.f, 0.f, 0.f, 0.f);
    float vmin = 1e30f, vmax = -1e30f;
    if (act) {
        const float4 p0 = ((const float4*)parts)[i];
        const float4 p1 = ((const float4*)(parts + NPIX))[i];
        const float4 p2 = ((const float4*)(parts + 2 * NPIX))[i];
        const float4 p3 = ((const float4*)(parts + 3 * NPIX))[i];
        im.x = (p0.x + p1.x) + (p2.x + p3.x);
        im.y = (p0.y + p1.y) + (p2.y + p3.y);
        im.z = (p0.z + p1.z) + (p2.z + p3.z);
        im.w = (p0.w + p1.w) + (p2.w + p3.w);
        const float4 nz = ((const float4*)noise)[i];
        im.x += sqrtf(fmaxf(im.x, 0.f) + SIGMA2) * nz.x;
        im.y += sqrtf(fmaxf(im.y, 0.f) + SIGMA2) * nz.y;
        im.z += sqrtf(fmaxf(im.z, 0.f) + SIGMA2) * nz.z;
        im.w += sqrtf(fmaxf(im.w, 0.f) + SIGMA2) * nz.w;
        vmin = fminf(fminf(im.x, im.y), fminf(im.z, im.w));
        vmax = fmaxf(fmaxf(im.x, im.y), fmaxf(im.z, im.w));
    }
    #pragma unroll
    for (int off = 32; off > 0; off >>= 1) {
        vmin = fminf(vmin, __shfl_down(vmin, off, 64));
        vmax = fmaxf(vmax, __shfl_down(vmax, off, 64));
    }
    if ((threadIdx.x & 63) == 0) {
        atomicMin(&minmax[0], enc_ord(vmin));
        atomicMax(&minmax[1], enc_ord(vmax));
    }
    __syncthreads();   /* drains the leaders' atomics (waitcnt before barrier) */

    if (threadIdx.x == 0) {
        __threadfence();
        atomicAdd(&minmax[2], 1u);
        unsigned v = __hip_atomic_load(&minmax[2], __ATOMIC_ACQUIRE, __HIP_MEMORY_SCOPE_AGENT);
        while (v < (unsigned)NMBLK) {
            __builtin_amdgcn_s_sleep(32);
            v = __hip_atomic_load(&minmax[2], __ATOMIC_ACQUIRE, __HIP_MEMORY_SCOPE_AGENT);
        }
        smm[0] = dec_ord(__hip_atomic_load(&minmax[0], __ATOMIC_RELAXED, __HIP_MEMORY_SCOPE_AGENT));
        smm[1] = dec_ord(__hip_atomic_load(&minmax[1], __ATOMIC_RELAXED, __HIP_MEMORY_SCOPE_AGENT));
    }
    __syncthreads();

    const float mn  = smm[0];
    const float inv = 1.0f / (smm[1] - mn);
    if (act) {
        float4 v;
        v.x = (im.x - mn) * inv;
        v.y = (im.y - mn) * inv;
        v.z = (im.z - mn) * inv;
        v.w = (im.w - mn) * inv;
        ((float4*)out)[i] = v;
    }
}

extern "C" void kernel_launch(void* const* d_in, const int* in_sizes, int n_in,
                              void* d_out, int out_size, void* d_ws, size_t ws_size,
                              hipStream_t stream) {
    const float* xyz      = (const float*)d_in[0];  /* (1,2048,3) */
    const float* nph      = (const float*)d_in[1];  /* (1,2048)   */
    /* d_in[2] = xy_center, unused by reference */
    const float* psf_bank = (const float*)d_in[3];  /* (64,121,121) */
    const float* noise    = (const float*)d_in[4];  /* (400,400) */
    float* out = (float*)d_out;

    /* ws layout (bytes):
       minmax: 0        .. 12         ([0]=min, [1]=max, [2]=done counter)
       zpart : 1024     .. 9216       (64 * 8 * float4)
       pad   : 9216     .. 5923840    (64 * 152 * 152 u32 f16x2)
       bucket: 5923840  .. 7562240    (100 * 512 * 2 float4)
       bcnt  : 7562240  .. 7562640    (100 ints)
       parts : 7563264  .. 10123264   (4 * 400*400 f32)            */
    char* ws = (char*)d_ws;
    unsigned* minmax = (unsigned*)(ws + 0);
    float*    zpart  = (float*)(ws + 1024);
    unsigned* pad    = (unsigned*)(ws + 9216);
    float4*   bucket = (float4*)(ws + 5923840);
    int*      bcnt   = (int*)(ws + 7562240);
    float*    parts  = (float*)(ws + 7563264);

    prep_kernel<<<PADBLK + NBUCK, 256, 0, stream>>>(psf_bank, zpart, pad, minmax,
                                                    xyz, nph, bucket, bcnt);
    gather_kernel<<<2504, 256, 0, stream>>>(pad, bucket, bcnt, zpart, parts);
    noise_norm_kernel<<<NMBLK, 256, 0, stream>>>(parts, noise, out, minmax);
}

// Round 21
// 55.140 us; speedup vs baseline: 1.4496x; 1.1109x over previous
//
#include <hip/hip_runtime.h>

#define H        400
#define W_CROP   400
#define PSF_W    121
#define MARGIN   44
#define IM       488
#define NZ       64
#define N_EMIT   2048
#define PSF_AREA (PSF_W * PSF_W)     /* 14641 */
#define SIGMA2   100.0f              /* SIGMA_READ^2 */
#define TILE     16
#define TB       25                  /* tiles per side: 400/16 */
#define NTILES   (TB * TB)           /* 625 */
#define NPIX     (H * W_CROP)        /* 160000 */
#define PADW     152                 /* padded slice width (rows/cols -16..135) */
#define PADA     (PADW * PADW)       /* 23104 elems per padded slice */
#define CHUNKS   4                   /* z-chunks (zi>>4) */
#define CAPC     224                 /* max emitters per (tile, z-chunk) */
#define CAP_B    512                 /* max emitters per (tile-row, z-chunk) bucket */
#define NBUCK    (TB * CHUNKS)       /* 100 */
#define PADBLK   512                 /* pad/zsum blocks in prep kernel */

typedef __fp16 h2 __attribute__((ext_vector_type(2)));

#if __has_builtin(__builtin_amdgcn_fdot2)
#define FDOT2(a, b, c) __builtin_amdgcn_fdot2((a), (b), (c), false)
#else
static __device__ __forceinline__ float FDOT2(h2 a, h2 b, float c) {
    return fmaf((float)a.x, (float)b.x, fmaf((float)a.y, (float)b.y, c));
}
#endif

static __device__ __forceinline__ unsigned pkh2(float lo, float hi) {
    const h2 v = __builtin_amdgcn_cvt_pkrtz(lo, hi);
    return __builtin_bit_cast(unsigned, v);
}

static __device__ __forceinline__ unsigned enc_ord(float f) {
    unsigned u = __float_as_uint(f);
    return (u & 0x80000000u) ? ~u : (u | 0x80000000u);
}
static __device__ __forceinline__ float dec_ord(unsigned u) {
    return __uint_as_float((u & 0x80000000u) ? (u & 0x7fffffffu) : ~u);
}

static __device__ __forceinline__ void geom_of(const float* __restrict__ xyz, int e,
                                               int& r0, int& c0, int& zi,
                                               float& r0f, float& c0f) {
    const float x = xyz[3 * e + 0];
    const float y = xyz[3 * e + 1];
    const float z = xyz[3 * e + 2];
    const float lx = (x * 100.0f) / 11.0f;
    const float ly = (y * 100.0f) / 11.0f;
    r0f = (ly + 244.0f) - 60.5f;
    c0f = (lx + 244.0f) - 60.5f;
    r0 = (int)floorf(r0f);
    c0 = (int)floorf(c0f);
    zi = (int)rintf((z + 2.0f) / 4.0f * 63.0f);
    zi = min(max(zi, 0), NZ - 1);
}

/* 612 blocks, two overlapped roles (proven r13/r15/r17 structure).
   bid < 512: (zi = bid>>3, part = bid&7) build PACKED-f16x2 padded slice
              part (u32 elem i = {f16 lo = psf[r][c-1] (ZEROED for c>120,
              baking the column crop into data), f16 hi = psf[r][c] << 16})
              + per-part f32 sums -> zpart. Block 0 inits minmax. No atomics.
   bid >= 512: bucket build. b = bid-512 = (tr, zc); scan all emitters,
              prefix-scan compact (e-ordered, deterministic) into bucket[b]. */
__global__ __launch_bounds__(256) void prep_kernel(
        const float* __restrict__ psf_bank, float* __restrict__ zpart,
        unsigned* __restrict__ pad, unsigned* __restrict__ minmax,
        const float* __restrict__ xyz, const float* __restrict__ nph_arr,
        float4* __restrict__ bucket, int* __restrict__ bcnt)
{
    __shared__ float red[4][4];
    __shared__ int   wtot[4];

    if (blockIdx.x < PADBLK) {
        const int zi   = blockIdx.x >> 3;
        const int part = blockIdx.x & 7;

        if (blockIdx.x == 0 && threadIdx.x == 0) { minmax[0] = 0xFFFFFFFFu; minmax[1] = 0u; }

        const float* __restrict__ src = psf_bank + (size_t)zi * PSF_AREA;
        unsigned* __restrict__ dst = pad + (size_t)zi * PADA;

        /* packed padded copy; part covers padded idx [part*2888, +2888).
           lo tap valid only for c in [1,120] (its sole consumer is pixel
           pc==c, invalid past 120) -> (c-1) < 120, NOT < 121. */
        const int plo = part * 2888;                 /* 2888 = 19*152 */
        const int phi = min(plo + 2888, PADA);
        for (int i = plo + (int)threadIdx.x; i < phi; i += 256) {
            const int rp = i / PADW;
            const int r = rp - 16;
            const int c = i - rp * PADW - 16;
            const bool rin = (unsigned)r < (unsigned)PSF_W;
            const float vm = (rin && (unsigned)(c - 1) < 120u)           ? src[r * PSF_W + c - 1] : 0.0f;
            const float vc = (rin && (unsigned)c < (unsigned)PSF_W)      ? src[r * PSF_W + c]     : 0.0f;
            dst[i] = pkh2(vm, vc);
        }

        const int slo = part * 1831;
        const int shi = min(slo + 1831, PSF_AREA);
        float S = 0.f, R = 0.f, C = 0.f, K = 0.f;
        for (int i = slo + (int)threadIdx.x; i < shi; i += 256) {
            const float v = src[i];
            const int r = i / PSF_W;
            const int c = i - r * PSF_W;
            S += v;
            if (r == PSF_W - 1) R += v;
            if (c == PSF_W - 1) C += v;
            if (r == PSF_W - 1 && c == PSF_W - 1) K += v;
        }
        #pragma unroll
        for (int off = 32; off > 0; off >>= 1) {
            S += __shfl_down(S, off, 64);
            R += __shfl_down(R, off, 64);
            C += __shfl_down(C, off, 64);
            K += __shfl_down(K, off, 64);
        }
        const int wave = threadIdx.x >> 6, lane = threadIdx.x & 63;
        if (lane == 0) { red[wave][0] = S; red[wave][1] = R; red[wave][2] = C; red[wave][3] = K; }
        __syncthreads();
        if (threadIdx.x == 0) {
            float4 o;
            o.x = (red[0][0] + red[1][0]) + (red[2][0] + red[3][0]);
            o.y = (red[0][1] + red[1][1]) + (red[2][1] + red[3][1]);
            o.z = (red[0][2] + red[1][2]) + (red[2][2] + red[3][2]);
            o.w = (red[0][3] + red[1][3]) + (red[2][3] + red[3][3]);
            *(float4*)(zpart + (size_t)(zi * 8 + part) * 4) = o;
        }
        return;
    }

    /* ---- bucket role ---- */
    const int b   = blockIdx.x - PADBLK;         /* 0..99 */
    const int btr = b >> 2, bzc = b & 3;
    const int w    = threadIdx.x >> 6;
    const int lane = threadIdx.x & 63;

    int mycnt = 0;
    unsigned mymask = 0u;
    #pragma unroll
    for (int q = 0; q < 8; ++q) {
        const int e = (int)threadIdx.x * 8 + q;
        int r0, c0, zi; float r0f, c0f;
        geom_of(xyz, e, r0, c0, zi, r0f, c0f);
        const bool p = ((zi >> 4) == bzc)
                     && (btr >= ((r0 - MARGIN) >> 4)) && (btr <= ((r0 + 76) >> 4));
        mymask |= (unsigned)p << q;
        mycnt += (int)p;
    }

    int incl = mycnt;
    #pragma unroll
    for (int off = 1; off < 64; off <<= 1) {
        const int v = __shfl_up(incl, off, 64);
        if (lane >= off) incl += v;
    }
    if (lane == 63) wtot[w] = incl;
    __syncthreads();
    int base = incl - mycnt;
    #pragma unroll
    for (int ww = 0; ww < 4; ++ww) base += (ww < w) ? wtot[ww] : 0;
    const int ntot = wtot[0] + wtot[1] + wtot[2] + wtot[3];

    if (mymask) {
        int slot = base;
        #pragma unroll
        for (int q = 0; q < 8; ++q) {
            if (mymask & (1u << q)) {
                const int e = (int)threadIdx.x * 8 + q;
                int r0, c0, zi; float r0f, c0f;
                geom_of(xyz, e, r0, c0, zi, r0f, c0f);
                if (slot < CAP_B) {
                    const float rs = r0f - floorf(r0f);
                    const float cs = c0f - floorf(c0f);
                    const float nph = nph_arr[e];
                    float4 s0, s1;
                    s0.x = nph * (1.0f - rs) * (1.0f - cs);
                    s0.y = nph * (1.0f - rs) * cs;
                    s0.z = nph * rs * (1.0f - cs);
                    s0.w = nph * rs * cs;
                    const int packed = ((r0 + 16) << 15) | ((c0 + 16) << 6) | zi;
                    s1.x = rs; s1.y = cs; s1.z = __int_as_float(packed); s1.w = 0.f;
                    bucket[(size_t)(b * CAP_B + slot) * 2]     = s0;
                    bucket[(size_t)(b * CAP_B + slot) * 2 + 1] = s1;
                }
                ++slot;
            }
        }
    }
    if (threadIdx.x == 0) bcnt[b] = min(ntot, CAP_B);
}

/* grid = 2504 blocks x 256 thr. XCD affinity: zc = (bid&7)>>1 pins each XCD
   pair to ONE z-chunk -> per-XCD pad working set = 1.48 MB (L2-resident).
   Staging: scan bucket (tr, zc), column test, wave-scan compaction, 1/ssum
   applied, weights packed to half2 -> ONE float4 per entry.
   Body: 1 LDS float4 + 5 dword loads + 8 v_dot2_f32_f16; column crop is in
   the data (pad zeros), row crop reduces to ONE compare (pr != 121).
   4-deep ILP unroll. Block partial -> LDS reduce -> partial image zc. */
__global__ __launch_bounds__(256) void gather_kernel(
        const unsigned* __restrict__ pad, const float4* __restrict__ bucket,
        const int* __restrict__ bcnt, const float* __restrict__ zpart,
        float* __restrict__ parts)
{
    const int zc   = (blockIdx.x & 7) >> 1;
    const int tile = 2 * (blockIdx.x >> 3) + (blockIdx.x & 1);
    if (tile >= NTILES) return;

    __shared__ float4 smeta[CAPC];               /* 3.6 KB */
    __shared__ float  tilepart[4][256];          /* 4 KB */
    __shared__ int    wtot[4];

    const int tr = tile / TB, tc = tile - tr * TB;
    const int w    = threadIdx.x >> 6;
    const int lane = threadIdx.x & 63;
    const int px = lane & 15;                    /* col within tile */
    const int wy = lane >> 4;                    /* 0..3: 4-row strip */
    const int orow0 = tr * TILE + wy * 4;
    const int ocol  = tc * TILE + px;
    const int crow0 = orow0 + MARGIN;            /* canvas coords */
    const int ccol  = ocol + MARGIN;
    const int tcb   = (crow0 * PADW + ccol) * 4; /* thread-const byte offset */
    const char* __restrict__ pbase = (const char*)pad;

    const int b   = tr * CHUNKS + zc;            /* bucket id */
    const int n_b = bcnt[b];
    const float4* __restrict__ bk = bucket + (size_t)b * CAP_B * 2;

    /* ---- staging: filter bucket entries by column range, compact e-ordered ---- */
    int nstaged = 0;
    for (int base_i = 0; base_i < n_b; base_i += 256) {
        const int i = base_i + (int)threadIdx.x;
        float4 m0, m1;
        int r0 = 0, c0 = 0, zi = 0;
        bool p = false;
        if (i < n_b) {
            m0 = bk[2 * i];
            m1 = bk[2 * i + 1];
            const int packed = __float_as_int(m1.z);
            zi = packed & 63;
            c0 = ((packed >> 6) & 511) - 16;
            r0 = ((packed >> 15) & 511) - 16;
            p = (tc >= ((c0 - MARGIN) >> 4)) && (tc <= ((c0 + 76) >> 4));
        }
        int incl = (int)p;
        #pragma unroll
        for (int off = 1; off < 64; off <<= 1) {
            const int v = __shfl_up(incl, off, 64);
            if (lane >= off) incl += v;
        }
        if (lane == 63) wtot[w] = incl;
        __syncthreads();
        int slot = nstaged + incl - (int)p;
        #pragma unroll
        for (int ww = 0; ww < 4; ++ww) slot += (ww < w) ? wtot[ww] : 0;
        const int round_tot = wtot[0] + wtot[1] + wtot[2] + wtot[3];
        if (p && slot < CAPC) {
            const float rs = m1.x, cs = m1.y;
            const float4* __restrict__ zp = (const float4*)zpart + zi * 8;
            float4 zm = zp[0];
            #pragma unroll
            for (int u = 1; u < 8; ++u) {
                const float4 t = zp[u];
                zm.x += t.x; zm.y += t.y; zm.z += t.z; zm.w += t.w;
            }
            const float ssum = zm.x - rs * zm.y - cs * zm.z + rs * cs * zm.w;
            const float inv = 1.0f / ssum;
            float4 s;
            s.x = __uint_as_float(pkh2(m0.y * inv, m0.x * inv));   /* {w01, w00} */
            s.y = __uint_as_float(pkh2(m0.w * inv, m0.z * inv));   /* {w11, w10} */
            s.z = __int_as_float((zi * PADA + (15 - r0) * PADW + (16 - c0)) * 4);
            s.w = __int_as_float(((r0 + 16) << 16) | (c0 + 16));
            smeta[slot] = s;
        }
        nstaged += round_tot;
        __syncthreads();
    }
    const int n = min(nstaged, CAPC);

    float acc0[4] = {0.f, 0.f, 0.f, 0.f};
    float acc1[4] = {0.f, 0.f, 0.f, 0.f};
    float acc2[4] = {0.f, 0.f, 0.f, 0.f};
    float acc3[4] = {0.f, 0.f, 0.f, 0.f};

    auto body = [&](int j, float* acc) {
        const float4 s = smeta[j];
        const h2 wA = __builtin_bit_cast(h2, s.x);      /* {w01, w00} */
        const h2 wB = __builtin_bit_cast(h2, s.y);      /* {w11, w10} */
        const int off = __float_as_int(s.z);
        const int rc  = __float_as_int(s.w);
        const int pr0 = crow0 - ((rc >> 16) - 16);      /* row of strip pixel 0 */
        const char* __restrict__ p = pbase + (tcb + off);
        h2 f[5];
        #pragma unroll
        for (int i = 0; i < 5; ++i)
            f[i] = __builtin_bit_cast(h2, *(const unsigned*)(p + i * (PADW * 4)));
        #pragma unroll
        for (int k = 0; k < 4; ++k) {
            float v = FDOT2(wA, f[k + 1], 0.0f);  /* w01*psf[pr][pc-1] + w00*psf[pr][pc] */
            v = FDOT2(wB, f[k], v);               /* w11*psf[pr-1][pc-1] + w10*psf[pr-1][pc] */
            /* column crop is baked into pad data; rows >121 and <0 read zeros.
               Sole residual invalid case: pr==121 pulls row 120 as prev-row. */
            acc[k] += (pr0 + k != 121) ? v : 0.f;
        }
    };

    int j = w;
    for (; j + 12 < n; j += 16) {
        body(j, acc0); body(j + 4, acc1); body(j + 8, acc2); body(j + 12, acc3);
    }
    for (; j < n; j += 4) body(j, acc0);

    #pragma unroll
    for (int k = 0; k < 4; ++k)
        tilepart[w][(wy * 4 + k) * 16 + px] = (acc0[k] + acc1[k]) + (acc2[k] + acc3[k]);
    __syncthreads();

    /* fixed-order reduce of the 4 waves, write partial image zc */
    const int row = threadIdx.x >> 4, col = threadIdx.x & 15;
    const float s = ((tilepart[0][threadIdx.x] + tilepart[1][threadIdx.x]) +
                     (tilepart[2][threadIdx.x] + tilepart[3][threadIdx.x]));
    parts[(size_t)zc * NPIX + (tr * TILE + row) * W_CROP + (tc * TILE + col)] = s;
}

/* sum 4 partial images (fixed order), apply noise, write out, reduce min/max */
__global__ __launch_bounds__(256) void noise_minmax_kernel(
        const float* __restrict__ parts, const float* __restrict__ noise,
        float* __restrict__ out, unsigned* __restrict__ minmax)
{
    const int i = blockIdx.x * 256 + threadIdx.x;
    float vmin = 1e30f, vmax = -1e30f;
    if (i < NPIX / 4) {
        const float4 p0 = ((const float4*)parts)[i];
        const float4 p1 = ((const float4*)(parts + NPIX))[i];
        const float4 p2 = ((const float4*)(parts + 2 * NPIX))[i];
        const float4 p3 = ((const float4*)(parts + 3 * NPIX))[i];
        float4 im;
        im.x = (p0.x + p1.x) + (p2.x + p3.x);
        im.y = (p0.y + p1.y) + (p2.y + p3.y);
        im.z = (p0.z + p1.z) + (p2.z + p3.z);
        im.w = (p0.w + p1.w) + (p2.w + p3.w);
        const float4 nz = ((const float4*)noise)[i];
        im.x += sqrtf(fmaxf(im.x, 0.f) + SIGMA2) * nz.x;
        im.y += sqrtf(fmaxf(im.y, 0.f) + SIGMA2) * nz.y;
        im.z += sqrtf(fmaxf(im.z, 0.f) + SIGMA2) * nz.z;
        im.w += sqrtf(fmaxf(im.w, 0.f) + SIGMA2) * nz.w;
        ((float4*)out)[i] = im;
        vmin = fminf(fminf(im.x, im.y), fminf(im.z, im.w));
        vmax = fmaxf(fmaxf(im.x, im.y), fmaxf(im.z, im.w));
    }
    #pragma unroll
    for (int off = 32; off > 0; off >>= 1) {
        vmin = fminf(vmin, __shfl_down(vmin, off, 64));
        vmax = fmaxf(vmax, __shfl_down(vmax, off, 64));
    }
    if ((threadIdx.x & 63) == 0) {
        atomicMin(&minmax[0], enc_ord(vmin));
        atomicMax(&minmax[1], enc_ord(vmax));
    }
}

__global__ __launch_bounds__(256) void finalize_kernel(float* __restrict__ out,
                                                       const unsigned* __restrict__ minmax)
{
    const int i = blockIdx.x * 256 + threadIdx.x;
    if (i >= NPIX / 4) return;
    const float mn = dec_ord(minmax[0]);
    const float inv = 1.0f / (dec_ord(minmax[1]) - mn);
    float4 v = ((float4*)out)[i];
    v.x = (v.x - mn) * inv;
    v.y = (v.y - mn) * inv;
    v.z = (v.z - mn) * inv;
    v.w = (v.w - mn) * inv;
    ((float4*)out)[i] = v;
}

extern "C" void kernel_launch(void* const* d_in, const int* in_sizes, int n_in,
                              void* d_out, int out_size, void* d_ws, size_t ws_size,
                              hipStream_t stream) {
    const float* xyz      = (const float*)d_in[0];  /* (1,2048,3) */
    const float* nph      = (const float*)d_in[1];  /* (1,2048)   */
    /* d_in[2] = xy_center, unused by reference */
    const float* psf_bank = (const float*)d_in[3];  /* (64,121,121) */
    const float* noise    = (const float*)d_in[4];  /* (400,400) */
    float* out = (float*)d_out;

    /* ws layout (bytes):
       minmax: 0        .. 8
       zpart : 1024     .. 9216       (64 * 8 * float4)
       pad   : 9216     .. 5923840    (64 * 152 * 152 u32 f16x2)
       bucket: 5923840  .. 7562240    (100 * 512 * 2 float4)
       bcnt  : 7562240  .. 7562640    (100 ints)
       parts : 7563264  .. 10123264   (4 * 400*400 f32)            */
    char* ws = (char*)d_ws;
    unsigned* minmax = (unsigned*)(ws + 0);
    float*    zpart  = (float*)(ws + 1024);
    unsigned* pad    = (unsigned*)(ws + 9216);
    float4*   bucket = (float4*)(ws + 5923840);
    int*      bcnt   = (int*)(ws + 7562240);
    float*    parts  = (float*)(ws + 7563264);

    prep_kernel<<<PADBLK + NBUCK, 256, 0, stream>>>(psf_bank, zpart, pad, minmax,
                                                    xyz, nph, bucket, bcnt);
    gather_kernel<<<2504, 256, 0, stream>>>(pad, bucket, bcnt, zpart, parts);
    noise_minmax_kernel<<<(NPIX / 4 + 255) / 256, 256, 0, stream>>>(parts, noise, out, minmax);
    finalize_kernel<<<(NPIX / 4 + 255) / 256, 256, 0, stream>>>(out, minmax);
}

// Round 22
// 54.660 us; speedup vs baseline: 1.4623x; 1.0088x over previous
//
#include <hip/hip_runtime.h>

#define H        400
#define W_CROP   400
#define PSF_W    121
#define MARGIN   44
#define IM       488
#define NZ       64
#define N_EMIT   2048
#define PSF_AREA (PSF_W * PSF_W)     /* 14641 */
#define SIGMA2   100.0f              /* SIGMA_READ^2 */
#define TILE     16
#define TB       25                  /* tiles per side: 400/16 */
#define NTILES   (TB * TB)           /* 625 */
#define NPIX     (H * W_CROP)        /* 160000 */
#define PADW     152                 /* padded slice width (rows/cols -16..135) */
#define PADA     (PADW * PADW)       /* 23104 elems per padded slice */
#define CHUNKS   4                   /* z-chunks (zi>>4) */
#define CAPC     224                 /* max emitters per (tile, z-chunk) */
#define CAP_B    512                 /* max emitters per (tile-row, z-chunk) bucket */
#define NBUCK    (TB * CHUNKS)       /* 100 */
#define PADBLK   1024                /* pad/zsum blocks in prep kernel (16 parts/z) */
#define PPART    16                  /* zsum parts per z-slice */

typedef __fp16 h2 __attribute__((ext_vector_type(2)));

#if __has_builtin(__builtin_amdgcn_fdot2)
#define FDOT2(a, b, c) __builtin_amdgcn_fdot2((a), (b), (c), false)
#else
static __device__ __forceinline__ float FDOT2(h2 a, h2 b, float c) {
    return fmaf((float)a.x, (float)b.x, fmaf((float)a.y, (float)b.y, c));
}
#endif

static __device__ __forceinline__ unsigned pkh2(float lo, float hi) {
    const h2 v = __builtin_amdgcn_cvt_pkrtz(lo, hi);
    return __builtin_bit_cast(unsigned, v);
}

static __device__ __forceinline__ unsigned enc_ord(float f) {
    unsigned u = __float_as_uint(f);
    return (u & 0x80000000u) ? ~u : (u | 0x80000000u);
}
static __device__ __forceinline__ float dec_ord(unsigned u) {
    return __uint_as_float((u & 0x80000000u) ? (u & 0x7fffffffu) : ~u);
}

static __device__ __forceinline__ void geom_of(const float* __restrict__ xyz, int e,
                                               int& r0, int& c0, int& zi,
                                               float& r0f, float& c0f) {
    const float x = xyz[3 * e + 0];
    const float y = xyz[3 * e + 1];
    const float z = xyz[3 * e + 2];
    const float lx = (x * 100.0f) / 11.0f;
    const float ly = (y * 100.0f) / 11.0f;
    r0f = (ly + 244.0f) - 60.5f;
    c0f = (lx + 244.0f) - 60.5f;
    r0 = (int)floorf(r0f);
    c0 = (int)floorf(c0f);
    zi = (int)rintf((z + 2.0f) / 4.0f * 63.0f);
    zi = min(max(zi, 0), NZ - 1);
}

/* 1124 blocks, two overlapped roles.
   bid < 1024: (zi = bid>>4, part = bid&15) build PACKED-f16x2 padded slice
              part (lo = psf[r][c-1] ZEROED for c>120 -> column crop in data;
              hi = psf[r][c]) + per-part f32 sums -> zpart[zi][part].
              4 blocks/CU (was 2) halves prep latency exposure. No atomics.
   bid >= 1024: bucket build. b = bid-1024 = (tr, zc); scan all emitters,
              ballot-compact (e-ordered, deterministic) into bucket[b]. */
__global__ __launch_bounds__(256) void prep_kernel(
        const float* __restrict__ psf_bank, float* __restrict__ zpart,
        unsigned* __restrict__ pad, unsigned* __restrict__ minmax,
        const float* __restrict__ xyz, const float* __restrict__ nph_arr,
        float4* __restrict__ bucket, int* __restrict__ bcnt)
{
    __shared__ float red[4][4];
    __shared__ int   wtot[4];

    if (blockIdx.x < PADBLK) {
        const int zi   = blockIdx.x >> 4;
        const int part = blockIdx.x & 15;

        if (blockIdx.x == 0 && threadIdx.x == 0) { minmax[0] = 0xFFFFFFFFu; minmax[1] = 0u; }

        const float* __restrict__ src = psf_bank + (size_t)zi * PSF_AREA;
        unsigned* __restrict__ dst = pad + (size_t)zi * PADA;

        /* packed padded copy; part covers padded idx [part*1444, +1444) */
        const int plo = part * 1444;                 /* 1444 = 23104/16 */
        const int phi = min(plo + 1444, PADA);
        for (int i = plo + (int)threadIdx.x; i < phi; i += 256) {
            const int rp = i / PADW;
            const int r = rp - 16;
            const int c = i - rp * PADW - 16;
            const bool rin = (unsigned)r < (unsigned)PSF_W;
            const float vm = (rin && (unsigned)(c - 1) < 120u)           ? src[r * PSF_W + c - 1] : 0.0f;
            const float vc = (rin && (unsigned)c < (unsigned)PSF_W)      ? src[r * PSF_W + c]     : 0.0f;
            dst[i] = pkh2(vm, vc);
        }

        /* f32 partial sums over original slice: [part*916, +916) */
        const int slo = part * 916;
        const int shi = min(slo + 916, PSF_AREA);
        float S = 0.f, R = 0.f, C = 0.f, K = 0.f;
        for (int i = slo + (int)threadIdx.x; i < shi; i += 256) {
            const float v = src[i];
            const int r = i / PSF_W;
            const int c = i - r * PSF_W;
            S += v;
            if (r == PSF_W - 1) R += v;
            if (c == PSF_W - 1) C += v;
            if (r == PSF_W - 1 && c == PSF_W - 1) K += v;
        }
        #pragma unroll
        for (int off = 32; off > 0; off >>= 1) {
            S += __shfl_down(S, off, 64);
            R += __shfl_down(R, off, 64);
            C += __shfl_down(C, off, 64);
            K += __shfl_down(K, off, 64);
        }
        const int wave = threadIdx.x >> 6, lane = threadIdx.x & 63;
        if (lane == 0) { red[wave][0] = S; red[wave][1] = R; red[wave][2] = C; red[wave][3] = K; }
        __syncthreads();
        if (threadIdx.x == 0) {
            float4 o;
            o.x = (red[0][0] + red[1][0]) + (red[2][0] + red[3][0]);
            o.y = (red[0][1] + red[1][1]) + (red[2][1] + red[3][1]);
            o.z = (red[0][2] + red[1][2]) + (red[2][2] + red[3][2]);
            o.w = (red[0][3] + red[1][3]) + (red[2][3] + red[3][3]);
            *(float4*)(zpart + (size_t)(zi * PPART + part) * 4) = o;
        }
        return;
    }

    /* ---- bucket role ---- */
    const int b   = blockIdx.x - PADBLK;         /* 0..99 */
    const int btr = b >> 2, bzc = b & 3;
    const int w    = threadIdx.x >> 6;
    const int lane = threadIdx.x & 63;

    int mycnt = 0;
    unsigned mymask = 0u;
    #pragma unroll
    for (int q = 0; q < 8; ++q) {
        const int e = (int)threadIdx.x * 8 + q;
        int r0, c0, zi; float r0f, c0f;
        geom_of(xyz, e, r0, c0, zi, r0f, c0f);
        const bool p = ((zi >> 4) == bzc)
                     && (btr >= ((r0 - MARGIN) >> 4)) && (btr <= ((r0 + 76) >> 4));
        mymask |= (unsigned)p << q;
        mycnt += (int)p;
    }

    int incl = mycnt;
    #pragma unroll
    for (int off = 1; off < 64; off <<= 1) {
        const int v = __shfl_up(incl, off, 64);
        if (lane >= off) incl += v;
    }
    if (lane == 63) wtot[w] = incl;
    __syncthreads();
    int base = incl - mycnt;
    #pragma unroll
    for (int ww = 0; ww < 4; ++ww) base += (ww < w) ? wtot[ww] : 0;
    const int ntot = wtot[0] + wtot[1] + wtot[2] + wtot[3];

    if (mymask) {
        int slot = base;
        #pragma unroll
        for (int q = 0; q < 8; ++q) {
            if (mymask & (1u << q)) {
                const int e = (int)threadIdx.x * 8 + q;
                int r0, c0, zi; float r0f, c0f;
                geom_of(xyz, e, r0, c0, zi, r0f, c0f);
                if (slot < CAP_B) {
                    const float rs = r0f - floorf(r0f);
                    const float cs = c0f - floorf(c0f);
                    const float nph = nph_arr[e];
                    float4 s0, s1;
                    s0.x = nph * (1.0f - rs) * (1.0f - cs);
                    s0.y = nph * (1.0f - rs) * cs;
                    s0.z = nph * rs * (1.0f - cs);
                    s0.w = nph * rs * cs;
                    const int packed = ((r0 + 16) << 15) | ((c0 + 16) << 6) | zi;
                    s1.x = rs; s1.y = cs; s1.z = __int_as_float(packed); s1.w = 0.f;
                    bucket[(size_t)(b * CAP_B + slot) * 2]     = s0;
                    bucket[(size_t)(b * CAP_B + slot) * 2 + 1] = s1;
                }
                ++slot;
            }
        }
    }
    if (threadIdx.x == 0) bcnt[b] = min(ntot, CAP_B);
}

/* grid = 2504 blocks x 256 thr. XCD affinity: zc = (bid&7)>>1 pins each XCD
   pair to ONE z-chunk -> per-XCD pad working set = 1.48 MB (L2-resident).
   Prologue: cooperative zmeta pre-reduction - 256 threads reduce the chunk's
   16 zi x 16 parts into szm[16] LDS (1 float4 load/thread + 16-lane shfl tree)
   -> staging reads 1 LDS entry instead of 8 global float4s per entry.
   Staging: scan bucket (tr, zc), column test, BALLOT+POPC compaction
   (e-ordered, deterministic), 1/ssum applied, weights packed to half2.
   Body: 1 LDS float4 + 5 dword loads + 8 v_dot2_f32_f16; column crop in data,
   row crop = ONE compare. 4-deep ILP unroll. LDS reduce -> partial image zc. */
__global__ __launch_bounds__(256) void gather_kernel(
        const unsigned* __restrict__ pad, const float4* __restrict__ bucket,
        const int* __restrict__ bcnt, const float* __restrict__ zpart,
        float* __restrict__ parts)
{
    const int zc   = (blockIdx.x & 7) >> 1;
    const int tile = 2 * (blockIdx.x >> 3) + (blockIdx.x & 1);
    if (tile >= NTILES) return;

    __shared__ float4 smeta[CAPC];               /* 3.6 KB */
    __shared__ float4 szm[16];                   /* per-chunk zi sums */
    __shared__ float  tilepart[4][256];          /* 4 KB */
    __shared__ int    wtot[4];

    const int tr = tile / TB, tc = tile - tr * TB;
    const int w    = threadIdx.x >> 6;
    const int lane = threadIdx.x & 63;
    const int px = lane & 15;                    /* col within tile */
    const int wy = lane >> 4;                    /* 0..3: 4-row strip */
    const int orow0 = tr * TILE + wy * 4;
    const int ocol  = tc * TILE + px;
    const int crow0 = orow0 + MARGIN;            /* canvas coords */
    const int ccol  = ocol + MARGIN;
    const int tcb   = (crow0 * PADW + ccol) * 4; /* thread-const byte offset */
    const char* __restrict__ pbase = (const char*)pad;

    /* ---- zmeta pre-reduction: zi = zc*16 + (tid>>4), part = tid&15 ---- */
    {
        const int zl = threadIdx.x >> 4;
        const int pt = threadIdx.x & 15;
        float4 v = ((const float4*)zpart)[(zc * 16 + zl) * PPART + pt];
        #pragma unroll
        for (int off = 8; off > 0; off >>= 1) {
            v.x += __shfl_down(v.x, off, 16);
            v.y += __shfl_down(v.y, off, 16);
            v.z += __shfl_down(v.z, off, 16);
            v.w += __shfl_down(v.w, off, 16);
        }
        if (pt == 0) szm[zl] = v;
    }
    __syncthreads();

    const int b   = tr * CHUNKS + zc;            /* bucket id */
    const int n_b = bcnt[b];
    const float4* __restrict__ bk = bucket + (size_t)b * CAP_B * 2;

    /* ---- staging: column filter + ballot compaction (e-ordered) ---- */
    int nstaged = 0;
    for (int base_i = 0; base_i < n_b; base_i += 256) {
        const int i = base_i + (int)threadIdx.x;
        float4 m0, m1;
        int r0 = 0, c0 = 0, zi = 0;
        bool p = false;
        if (i < n_b) {
            m0 = bk[2 * i];
            m1 = bk[2 * i + 1];
            const int packed = __float_as_int(m1.z);
            zi = packed & 63;
            c0 = ((packed >> 6) & 511) - 16;
            r0 = ((packed >> 15) & 511) - 16;
            p = (tc >= ((c0 - MARGIN) >> 4)) && (tc <= ((c0 + 76) >> 4));
        }
        const unsigned long long m = __ballot(p);
        const int before = __popcll(m & ((1ULL << lane) - 1ULL));
        if (lane == 63) wtot[w] = before + (int)p;
        __syncthreads();
        int slot = nstaged + before;
        #pragma unroll
        for (int ww = 0; ww < 4; ++ww) slot += (ww < w) ? wtot[ww] : 0;
        const int round_tot = wtot[0] + wtot[1] + wtot[2] + wtot[3];
        if (p && slot < CAPC) {
            const float rs = m1.x, cs = m1.y;
            const float4 zm = szm[zi & 15];
            const float ssum = zm.x - rs * zm.y - cs * zm.z + rs * cs * zm.w;
            const float inv = 1.0f / ssum;
            float4 s;
            s.x = __uint_as_float(pkh2(m0.y * inv, m0.x * inv));   /* {w01, w00} */
            s.y = __uint_as_float(pkh2(m0.w * inv, m0.z * inv));   /* {w11, w10} */
            s.z = __int_as_float((zi * PADA + (15 - r0) * PADW + (16 - c0)) * 4);
            s.w = __int_as_float(((r0 + 16) << 16) | (c0 + 16));
            smeta[slot] = s;
        }
        nstaged += round_tot;
        __syncthreads();
    }
    const int n = min(nstaged, CAPC);

    float acc0[4] = {0.f, 0.f, 0.f, 0.f};
    float acc1[4] = {0.f, 0.f, 0.f, 0.f};
    float acc2[4] = {0.f, 0.f, 0.f, 0.f};
    float acc3[4] = {0.f, 0.f, 0.f, 0.f};

    auto body = [&](int j, float* acc) {
        const float4 s = smeta[j];
        const h2 wA = __builtin_bit_cast(h2, s.x);      /* {w01, w00} */
        const h2 wB = __builtin_bit_cast(h2, s.y);      /* {w11, w10} */
        const int off = __float_as_int(s.z);
        const int rc  = __float_as_int(s.w);
        const int pr0 = crow0 - ((rc >> 16) - 16);      /* row of strip pixel 0 */
        const char* __restrict__ p = pbase + (tcb + off);
        h2 f[5];
        #pragma unroll
        for (int i = 0; i < 5; ++i)
            f[i] = __builtin_bit_cast(h2, *(const unsigned*)(p + i * (PADW * 4)));
        #pragma unroll
        for (int k = 0; k < 4; ++k) {
            float v = FDOT2(wA, f[k + 1], 0.0f);  /* w01*psf[pr][pc-1] + w00*psf[pr][pc] */
            v = FDOT2(wB, f[k], v);               /* w11*psf[pr-1][pc-1] + w10*psf[pr-1][pc] */
            /* column crop baked into pad; only invalid residual: pr==121 */
            acc[k] += (pr0 + k != 121) ? v : 0.f;
        }
    };

    int j = w;
    for (; j + 12 < n; j += 16) {
        body(j, acc0); body(j + 4, acc1); body(j + 8, acc2); body(j + 12, acc3);
    }
    for (; j < n; j += 4) body(j, acc0);

    #pragma unroll
    for (int k = 0; k < 4; ++k)
        tilepart[w][(wy * 4 + k) * 16 + px] = (acc0[k] + acc1[k]) + (acc2[k] + acc3[k]);
    __syncthreads();

    /* fixed-order reduce of the 4 waves, write partial image zc */
    const int row = threadIdx.x >> 4, col = threadIdx.x & 15;
    const float s = ((tilepart[0][threadIdx.x] + tilepart[1][threadIdx.x]) +
                     (tilepart[2][threadIdx.x] + tilepart[3][threadIdx.x]));
    parts[(size_t)zc * NPIX + (tr * TILE + row) * W_CROP + (tc * TILE + col)] = s;
}

/* sum 4 partial images (fixed order), apply noise, write out, reduce min/max */
__global__ __launch_bounds__(256) void noise_minmax_kernel(
        const float* __restrict__ parts, const float* __restrict__ noise,
        float* __restrict__ out, unsigned* __restrict__ minmax)
{
    const int i = blockIdx.x * 256 + threadIdx.x;
    float vmin = 1e30f, vmax = -1e30f;
    if (i < NPIX / 4) {
        const float4 p0 = ((const float4*)parts)[i];
        const float4 p1 = ((const float4*)(parts + NPIX))[i];
        const float4 p2 = ((const float4*)(parts + 2 * NPIX))[i];
        const float4 p3 = ((const float4*)(parts + 3 * NPIX))[i];
        float4 im;
        im.x = (p0.x + p1.x) + (p2.x + p3.x);
        im.y = (p0.y + p1.y) + (p2.y + p3.y);
        im.z = (p0.z + p1.z) + (p2.z + p3.z);
        im.w = (p0.w + p1.w) + (p2.w + p3.w);
        const float4 nz = ((const float4*)noise)[i];
        im.x += sqrtf(fmaxf(im.x, 0.f) + SIGMA2) * nz.x;
        im.y += sqrtf(fmaxf(im.y, 0.f) + SIGMA2) * nz.y;
        im.z += sqrtf(fmaxf(im.z, 0.f) + SIGMA2) * nz.z;
        im.w += sqrtf(fmaxf(im.w, 0.f) + SIGMA2) * nz.w;
        ((float4*)out)[i] = im;
        vmin = fminf(fminf(im.x, im.y), fminf(im.z, im.w));
        vmax = fmaxf(fmaxf(im.x, im.y), fmaxf(im.z, im.w));
    }
    #pragma unroll
    for (int off = 32; off > 0; off >>= 1) {
        vmin = fminf(vmin, __shfl_down(vmin, off, 64));
        vmax = fmaxf(vmax, __shfl_down(vmax, off, 64));
    }
    if ((threadIdx.x & 63) == 0) {
        atomicMin(&minmax[0], enc_ord(vmin));
        atomicMax(&minmax[1], enc_ord(vmax));
    }
}

__global__ __launch_bounds__(256) void finalize_kernel(float* __restrict__ out,
                                                       const unsigned* __restrict__ minmax)
{
    const int i = blockIdx.x * 256 + threadIdx.x;
    if (i >= NPIX / 4) return;
    const float mn = dec_ord(minmax[0]);
    const float inv = 1.0f / (dec_ord(minmax[1]) - mn);
    float4 v = ((float4*)out)[i];
    v.x = (v.x - mn) * inv;
    v.y = (v.y - mn) * inv;
    v.z = (v.z - mn) * inv;
    v.w = (v.w - mn) * inv;
    ((float4*)out)[i] = v;
}

extern "C" void kernel_launch(void* const* d_in, const int* in_sizes, int n_in,
                              void* d_out, int out_size, void* d_ws, size_t ws_size,
                              hipStream_t stream) {
    const float* xyz      = (const float*)d_in[0];  /* (1,2048,3) */
    const float* nph      = (const float*)d_in[1];  /* (1,2048)   */
    /* d_in[2] = xy_center, unused by reference */
    const float* psf_bank = (const float*)d_in[3];  /* (64,121,121) */
    const float* noise    = (const float*)d_in[4];  /* (400,400) */
    float* out = (float*)d_out;

    /* ws layout (bytes):
       minmax: 0        .. 8
       zpart : 1024     .. 17408      (64 * 16 * float4)
       pad   : 17408    .. 5932032    (64 * 152 * 152 u32 f16x2)
       bucket: 5932032  .. 7570432    (100 * 512 * 2 float4)
       bcnt  : 7570432  .. 7570832    (100 ints)
       parts : 7571456  .. 10131456   (4 * 400*400 f32)            */
    char* ws = (char*)d_ws;
    unsigned* minmax = (unsigned*)(ws + 0);
    float*    zpart  = (float*)(ws + 1024);
    unsigned* pad    = (unsigned*)(ws + 17408);
    float4*   bucket = (float4*)(ws + 5932032);
    int*      bcnt   = (int*)(ws + 7570432);
    float*    parts  = (float*)(ws + 7571456);

    prep_kernel<<<PADBLK + NBUCK, 256, 0, stream>>>(psf_bank, zpart, pad, minmax,
                                                    xyz, nph, bucket, bcnt);
    gather_kernel<<<2504, 256, 0, stream>>>(pad, bucket, bcnt, zpart, parts);
    noise_minmax_kernel<<<(NPIX / 4 + 255) / 256, 256, 0, stream>>>(parts, noise, out, minmax);
    finalize_kernel<<<(NPIX / 4 + 255) / 256, 256, 0, stream>>>(out, minmax);
}